// Round 1
// baseline (742.110 us; speedup 1.0000x reference)
//
#include <hip/hip_runtime.h>

#define TB 128      // T
#define BB 8        // B
#define MM 8        // instruments
#define KP 16       // keypoints per instrument
#define KR 17       // K + root
#define NN 136      // M*KR
#define EMB 64
#define HID 128
#define G4 512      // 4*HID
#define BN 1088     // B*N
#define NEG_SLOPE 0.2f

__device__ __forceinline__ float sigf(float x) { return 1.0f/(1.0f + __expf(-x)); }
__device__ __forceinline__ float tanhf_fast(float x) {
  x = fminf(fmaxf(x, -15.0f), 15.0f);
  float e = __expf(2.0f*x);
  return (e - 1.0f)/(e + 1.0f);
}
// barrier that drains only LDS (lgkm), NOT global stores (vmcnt) — all
// cross-wave data in k2 flows through LDS; global r-stores are fire-and-forget.
__device__ __forceinline__ void bar_lds() {
  asm volatile("s_waitcnt lgkmcnt(0)\n\ts_barrier" ::: "memory");
}

// ---------------------------------------------------------------------------
// K1: root synthesis + 2-layer MLP -> x[t][b*NN+n][e]  (one block per (b,t))
// ---------------------------------------------------------------------------
__global__ __launch_bounds__(256) void k1_mlp(
    const float* __restrict__ feat, const float* __restrict__ W1,
    const float* __restrict__ b1, const float* __restrict__ W2,
    const float* __restrict__ b2, float* __restrict__ x)
{
  __shared__ float fl[MM*KP*3];
  __shared__ float fR[NN][3];
  __shared__ float hidl[NN][EMB];
  const int bt = blockIdx.x;
  const int b = bt >> 7;          // bt / T  (T == 128)
  const int t = bt & 127;
  const int tid = threadIdx.x;

  const float* fp = feat + (size_t)bt * (MM*KP*3);
  for (int i = tid; i < MM*KP*3; i += 256) fl[i] = fp[i];
  __syncthreads();

  if (tid < NN) {
    int n = tid, m = n / KR, kk = n - m*KR;
    if (kk < KP) {
      fR[n][0] = fl[(m*KP+kk)*3+0];
      fR[n][1] = fl[(m*KP+kk)*3+1];
      fR[n][2] = fl[(m*KP+kk)*3+2];
    } else {
      float sx = 0.f, sy = 0.f, sw = 0.f;
      for (int k = 0; k < KP; ++k) {
        float vz = fl[(m*KP+k)*3+2];
        float w = (vz > 0.5f) ? 1.0f : 0.0f;
        sx += fl[(m*KP+k)*3+0]*w;
        sy += fl[(m*KP+k)*3+1]*w;
        sw += w;
      }
      float dn = fmaxf(sw, 1.0f);
      fR[n][0] = sx/dn; fR[n][1] = sy/dn; fR[n][2] = (sw > 0.f) ? 1.f : 0.f;
    }
  }
  __syncthreads();

  const int p = tid & 31, e0 = p*2, nb = tid >> 5;   // 8 row-groups of 17
  float w10a = W1[e0],   w11a = W1[EMB+e0],   w12a = W1[2*EMB+e0],   b1a = b1[e0];
  float w10b = W1[e0+1], w11b = W1[EMB+e0+1], w12b = W1[2*EMB+e0+1], b1b = b1[e0+1];
  for (int ni = 0; ni < 17; ++ni) {
    int n = nb*17 + ni;
    float xx = fR[n][0], yy = fR[n][1], zz = fR[n][2];
    float va = fmaf(xx,w10a, fmaf(yy,w11a, fmaf(zz,w12a, b1a)));
    float vb = fmaf(xx,w10b, fmaf(yy,w11b, fmaf(zz,w12b, b1b)));
    *(float2*)&hidl[n][e0] = make_float2(fmaxf(va,0.f), fmaxf(vb,0.f));
  }
  float2 w2c[EMB];
  #pragma unroll
  for (int j = 0; j < EMB; ++j) w2c[j] = *(const float2*)&W2[(size_t)j*EMB + e0];
  float b2a = b2[e0], b2b = b2[e0+1];
  __syncthreads();

  float* xo = x + ((size_t)t*BN + (size_t)b*NN)*EMB + e0;
  for (int ni = 0; ni < 17; ++ni) {
    int n = nb*17 + ni;
    float aa = b2a, ab = b2b;
    const float4* h4 = (const float4*)hidl[n];
    #pragma unroll
    for (int j4 = 0; j4 < 16; ++j4) {
      float4 hv = h4[j4];
      aa = fmaf(hv.x, w2c[4*j4+0].x, aa); ab = fmaf(hv.x, w2c[4*j4+0].y, ab);
      aa = fmaf(hv.y, w2c[4*j4+1].x, aa); ab = fmaf(hv.y, w2c[4*j4+1].y, ab);
      aa = fmaf(hv.z, w2c[4*j4+2].x, aa); ab = fmaf(hv.z, w2c[4*j4+2].y, ab);
      aa = fmaf(hv.w, w2c[4*j4+3].x, aa); ab = fmaf(hv.w, w2c[4*j4+3].y, ab);
    }
    *(float2*)&xo[(size_t)n*EMB] = make_float2(aa, ab);
  }
}

// ---------------------------------------------------------------------------
// K2: LSTM, gate-split + split-k across 16 waves. 256 blocks x 1024 threads.
// Wave-group 0 (waves 0-7) owns gates 0..255, group 1 (waves 8-15) owns
// 256..511; within a group wave kw owns k-chunk [kw*24, kw*24+24). Lane owns
// 4 gate rows x 24 k = 96 weight VGPRs -> fits the 128-VGPR budget of
// 4 waves/SIMD (vs previous 192 regs @ 2 waves/SIMD, which left the SIMD
// idle 45% on LDS/barrier latency). zp layout and reduce are unchanged.
// lgkm-only barriers (global stores never drained); x-prefetch issued BEFORE
// r-stores so its vmcnt wait doesn't drain stores. Biases live in LDS to
// save VGPRs.
// ---------------------------------------------------------------------------
__global__ __launch_bounds__(1024, 4) void k2_lstm(
    const float* __restrict__ x, const float* __restrict__ W_ih,
    const float* __restrict__ W_hh, const float* __restrict__ b_ih,
    const float* __restrict__ b_hh, float* __restrict__ r)
{
  __shared__ float vl[5*192];        // per-seq [x(64) | h(128)]
  __shared__ float zp[5*8*512];      // partials [s][kchunk][gate]  (80 KB)
  __shared__ float bsum[G4];         // b_ih + b_hh
  const int blk = blockIdx.x;
  const int s0 = blk*4 + min(blk, 64);   // balanced partition of 1088
  const int S  = (blk < 64) ? 5 : 4;
  const int tid = threadIdx.x;
  const int wid = tid >> 6;          // wave 0..15
  const int l   = tid & 63;
  const int kw  = wid & 7;           // k-chunk index
  const int k0  = kw * 24;           // this wave's k-chunk base
  const int gbase = (wid >> 3)*256 + l*4;   // 4 gate rows owned by this lane

  // --- weights into registers (pin with asm so the compiler can't remat) ---
  float w[4][24];
  #pragma unroll
  for (int i = 0; i < 4; ++i) {
    int g = gbase + i;
    #pragma unroll
    for (int j = 0; j < 24; ++j) {
      int k = k0 + j;
      w[i][j] = (k < 64) ? W_ih[(size_t)g*64 + k] : W_hh[(size_t)g*128 + (k-64)];
    }
  }
  #pragma unroll
  for (int i = 0; i < 4; ++i)
    #pragma unroll
    for (int j = 0; j < 24; ++j)
      asm volatile("" : "+v"(w[i][j]));

  // reducer-side: thread (tid < S*128) handles (seq s = tid>>7, hidden jr)
  const int jr = tid & 127;

  // precomputed r-store address
  float* rp0 = nullptr;
  if (tid < S*128) {
    int s = tid>>7, q = s0+s, b = q/NN, n = q-b*NN;
    rp0 = r + (((size_t)b*TB)*NN + n)*HID + jr;
  }
  const size_t rstep = (size_t)NN*HID;

  // init: biases, h=0, x(t=0)
  for (int i = tid; i < G4; i += 1024) bsum[i] = b_ih[i] + b_hh[i];
  if (tid < 5*128) vl[(tid>>7)*192 + 64 + (tid&127)] = 0.f;
  if (tid < S*64)  vl[(tid>>6)*192 + (tid&63)] = x[(size_t)s0*EMB + tid];
  __syncthreads();

  float c0 = 0.f;

  for (int t = 0; t < TB; ++t) {
    // prefetch x_{t+1} FIRST (oldest vmem entry -> later wait won't drain stores)
    float xpre = 0.f;
    {
      int tp = (t+1 < TB) ? t+1 : t;
      if (tid < S*64) xpre = x[((size_t)tp*BN + s0)*EMB + tid];
    }
    // partial z over this wave's k-chunk for its 4 gate rows
    for (int s = 0; s < S; ++s) {
      float a[4] = {0.f,0.f,0.f,0.f};
      const float4* vs = (const float4*)(vl + s*192 + k0);
      #pragma unroll
      for (int j4 = 0; j4 < 6; ++j4) {
        float4 vv = vs[j4];
        #pragma unroll
        for (int i = 0; i < 4; ++i) {
          a[i] = fmaf(vv.x, w[i][j4*4+0], a[i]);
          a[i] = fmaf(vv.y, w[i][j4*4+1], a[i]);
          a[i] = fmaf(vv.z, w[i][j4*4+2], a[i]);
          a[i] = fmaf(vv.w, w[i][j4*4+3], a[i]);
        }
      }
      *(float4*)(zp + (s*8 + kw)*512 + gbase) = make_float4(a[0],a[1],a[2],a[3]);
    }
    bar_lds();
    // fused cross-wave reduce + gates + DIRECT r-store (fire-and-forget)
    if (tid < S*128) {
      int s = tid>>7;
      float zi = bsum[jr],     zf = bsum[128+jr];
      float zg = bsum[256+jr], zo = bsum[384+jr];
      #pragma unroll
      for (int ww = 0; ww < 8; ++ww) {
        const float* zb0 = zp + (s*8 + ww)*512 + jr;   // read2: {0,+128}
        const float* zb1 = zb0 + 256;                  // read2: {0,+128}
        zi += zb0[0]; zf += zb0[128];
        zg += zb1[0]; zo += zb1[128];
      }
      float c = sigf(zf)*c0 + sigf(zi)*tanhf_fast(zg);
      float h = sigf(zo)*tanhf_fast(c);
      c0 = c;
      vl[s*192 + 64 + jr] = h;
      rp0[(size_t)t*rstep] = h;
    }
    // publish prefetched x (vmcnt wait here only covers the x load)
    if (tid < S*64) vl[(tid>>6)*192 + (tid&63)] = xpre;
    bar_lds();
  }
}

// ---------------------------------------------------------------------------
// K3: GAT. s = r@(Wg@a) matvecs; agg in r-space; ONE 16x128x128 GEMM
// H2=[r_roots;aggR]@Wg with coalesced Wg loads and broadcast V^T from LDS.
// ---------------------------------------------------------------------------
__global__ __launch_bounds__(256) void k3_gat(
    const float* __restrict__ r, const float* __restrict__ Wg,
    const float* __restrict__ a_src, const float* __restrict__ a_dst,
    float* __restrict__ rhat)
{
  __shared__ float rl[NN*132];          // r rows padded to 132 floats (71.8 KB)
  __shared__ float waS[HID], waD[HID];
  __shared__ float ssrc[NN], sdst[NN];
  __shared__ float alpha[MM][24];
  __shared__ float aggR[MM][HID];
  __shared__ float v16[HID*20];         // V^T [k][row], row-pad 20 (16B-aligned)
  __shared__ float h2[16][HID];
  const int bt = blockIdx.x;
  const int tid = threadIdx.x;
  const float* rb = r + (size_t)bt*NN*HID;

  // stage r
  {
    const float4* rb4 = (const float4*)rb;
    for (int i = tid; i < NN*32; i += 256) {
      int n = i >> 5, k4 = i & 31;
      *(float4*)&rl[n*132 + k4*4] = rb4[i];
    }
  }
  // wa = Wg @ a  (two 128-dot columns over 256 threads)
  {
    int half = tid >> 7, j = tid & 127;
    const float* av = half ? a_dst : a_src;
    float acc = 0.f;
    for (int k = 0; k < HID; ++k) acc = fmaf(Wg[(size_t)k*HID + j], av[k], acc);
    if (half) waD[j] = acc; else waS[j] = acc;
  }
  __syncthreads();
  // scores
  for (int job = tid; job < 2*NN; job += 256) {
    int n = job >> 1, which = job & 1;
    const float4* rn = (const float4*)&rl[n*132];
    const float4* wa = (const float4*)(which ? waD : waS);
    float acc = 0.f;
    #pragma unroll
    for (int i = 0; i < 32; ++i) {
      float4 a4 = rn[i], b4 = wa[i];
      acc = fmaf(a4.x,b4.x, fmaf(a4.y,b4.y, fmaf(a4.z,b4.z, fmaf(a4.w,b4.w, acc))));
    }
    if (which) sdst[n] = acc; else ssrc[n] = acc;
  }
  __syncthreads();
  // softmax over each root's 23 incoming edges
  if (tid < MM) {
    int m = tid;
    float sd = sdst[m*KR + KP];
    float ev[23]; float mx = -1e30f;
    #pragma unroll
    for (int k = 0; k < 23; ++k) {
      int srcn;
      if (k < KP) srcn = m*KR + k;
      else { int rr = k - KP; rr += (rr >= m) ? 1 : 0; srcn = rr*KR + KP; }
      float e = ssrc[srcn] + sd;
      e = (e > 0.f) ? e : NEG_SLOPE*e;
      ev[k] = e; mx = fmaxf(mx, e);
    }
    float den = 0.f;
    #pragma unroll
    for (int k = 0; k < 23; ++k) { float ex = __expf(ev[k]-mx); ev[k] = ex; den += ex; }
    float inv = 1.f/den;
    #pragma unroll
    for (int k = 0; k < 23; ++k) alpha[m][k] = ev[k]*inv;
  }
  __syncthreads();
  // aggregate in r-space
  {
    int m = tid >> 5, jq = (tid & 31)*4;
    float4 acc = make_float4(0.f,0.f,0.f,0.f);
    #pragma unroll
    for (int k = 0; k < 23; ++k) {
      int srcn;
      if (k < KP) srcn = m*KR + k;
      else { int rr = k - KP; rr += (rr >= m) ? 1 : 0; srcn = rr*KR + KP; }
      float al = alpha[m][k];
      float4 hv = *(const float4*)&rl[srcn*132 + jq];
      acc.x = fmaf(al, hv.x, acc.x); acc.y = fmaf(al, hv.y, acc.y);
      acc.z = fmaf(al, hv.z, acc.z); acc.w = fmaf(al, hv.w, acc.w);
    }
    *(float4*)&aggR[m][jq] = acc;
  }
  __syncthreads();
  // build V^T: v16[k][row] = (row<8 ? r_root[row][k] : aggR[row-8][k])
  for (int idx = tid; idx < 16*HID; idx += 256) {
    int k = idx & 127, row = idx >> 7;
    float v = (row < 8) ? rl[(row*KR + KP)*132 + k] : aggR[row-8][k];
    v16[k*20 + row] = v;
  }
  __syncthreads();
  // H2 = V(16x128) @ Wg(128x128): thread = (row-half, col j).
  // Wg: one coalesced b32/iter (L2-hot); V^T: all-lane-broadcast float4s.
  {
    int half = tid >> 7, j = tid & 127;
    float acc[8] = {0.f,0.f,0.f,0.f,0.f,0.f,0.f,0.f};
    const float* wgp = Wg + j;
    #pragma unroll 4
    for (int k = 0; k < HID; ++k) {
      float wv = wgp[(size_t)k*HID];
      const float4* vv = (const float4*)&v16[k*20 + half*8];
      float4 va = vv[0], vb = vv[1];
      acc[0] = fmaf(va.x, wv, acc[0]); acc[1] = fmaf(va.y, wv, acc[1]);
      acc[2] = fmaf(va.z, wv, acc[2]); acc[3] = fmaf(va.w, wv, acc[3]);
      acc[4] = fmaf(vb.x, wv, acc[4]); acc[5] = fmaf(vb.y, wv, acc[5]);
      acc[6] = fmaf(vb.z, wv, acc[6]); acc[7] = fmaf(vb.w, wv, acc[7]);
    }
    #pragma unroll
    for (int q = 0; q < 8; ++q) h2[half*8 + q][j] = acc[q];
  }
  __syncthreads();
  // output: leaves elu(H2[m]); roots elu(H2[8+m]); coalesced over j
  {
    int j = tid & 127, half = tid >> 7;
    float* out = rhat + (size_t)bt*NN*HID + j;
    for (int ni = 0; ni < 68; ++ni) {
      int n = half*68 + ni;
      int m = n / KR, kk = n - m*KR;
      float v = (kk < KP) ? h2[m][j] : h2[8+m][j];
      v = (v > 0.f) ? v : (__expf(v) - 1.f);
      out[(size_t)n*HID] = v;
    }
  }
}

// ---------------------------------------------------------------------------
extern "C" void kernel_launch(void* const* d_in, const int* in_sizes, int n_in,
                              void* d_out, int out_size, void* d_ws, size_t ws_size,
                              hipStream_t stream) {
  (void)in_sizes; (void)n_in; (void)out_size; (void)ws_size;
  const float* feat  = (const float*)d_in[0];
  const float* W1    = (const float*)d_in[1];
  const float* b1    = (const float*)d_in[2];
  const float* W2    = (const float*)d_in[3];
  const float* b2    = (const float*)d_in[4];
  const float* W_ih  = (const float*)d_in[5];
  const float* W_hh  = (const float*)d_in[6];
  const float* b_ih  = (const float*)d_in[7];
  const float* b_hh  = (const float*)d_in[8];
  const float* Wg    = (const float*)d_in[9];
  const float* a_src = (const float*)d_in[10];
  const float* a_dst = (const float*)d_in[11];

  float* x    = (float*)d_ws;                       // (T, B*N, EMB) fp32 = 35.7 MB
  float* r    = (float*)d_out;                      // (B, T, N, HID)
  float* rhat = r + (size_t)BB*TB*NN*HID;           // (B, T, N, HID)

  k1_mlp<<<BB*TB, 256, 0, stream>>>(feat, W1, b1, W2, b2, x);
  k2_lstm<<<256, 1024, 0, stream>>>(x, W_ih, W_hh, b_ih, b_hh, r);
  k3_gat<<<BB*TB, 256, 0, stream>>>(r, Wg, a_src, a_dst, rhat);
}

// Round 2
// 740.480 us; speedup vs baseline: 1.0022x; 1.0022x over previous
//
#include <hip/hip_runtime.h>

#define TB 128      // T
#define BB 8        // B
#define MM 8        // instruments
#define KP 16       // keypoints per instrument
#define KR 17       // K + root
#define NN 136      // M*KR
#define EMB 64
#define HID 128
#define G4 512      // 4*HID
#define BN 1088     // B*N
#define NEG_SLOPE 0.2f

__device__ __forceinline__ float sigf(float x) { return 1.0f/(1.0f + __expf(-x)); }
__device__ __forceinline__ float tanhf_fast(float x) {
  x = fminf(fmaxf(x, -15.0f), 15.0f);
  float e = __expf(2.0f*x);
  return (e - 1.0f)/(e + 1.0f);
}
// barrier that drains only LDS (lgkm), NOT global stores (vmcnt) — all
// cross-wave data in k2 flows through LDS; global r-stores are fire-and-forget.
__device__ __forceinline__ void bar_lds() {
  asm volatile("s_waitcnt lgkmcnt(0)\n\ts_barrier" ::: "memory");
}

// ---------------------------------------------------------------------------
// K1: root synthesis + 2-layer MLP -> x[t][b*NN+n][e]  (one block per (b,t))
// ---------------------------------------------------------------------------
__global__ __launch_bounds__(256) void k1_mlp(
    const float* __restrict__ feat, const float* __restrict__ W1,
    const float* __restrict__ b1, const float* __restrict__ W2,
    const float* __restrict__ b2, float* __restrict__ x)
{
  __shared__ float fl[MM*KP*3];
  __shared__ float fR[NN][3];
  __shared__ float hidl[NN][EMB];
  const int bt = blockIdx.x;
  const int b = bt >> 7;          // bt / T  (T == 128)
  const int t = bt & 127;
  const int tid = threadIdx.x;

  const float* fp = feat + (size_t)bt * (MM*KP*3);
  for (int i = tid; i < MM*KP*3; i += 256) fl[i] = fp[i];
  __syncthreads();

  if (tid < NN) {
    int n = tid, m = n / KR, kk = n - m*KR;
    if (kk < KP) {
      fR[n][0] = fl[(m*KP+kk)*3+0];
      fR[n][1] = fl[(m*KP+kk)*3+1];
      fR[n][2] = fl[(m*KP+kk)*3+2];
    } else {
      float sx = 0.f, sy = 0.f, sw = 0.f;
      for (int k = 0; k < KP; ++k) {
        float vz = fl[(m*KP+k)*3+2];
        float w = (vz > 0.5f) ? 1.0f : 0.0f;
        sx += fl[(m*KP+k)*3+0]*w;
        sy += fl[(m*KP+k)*3+1]*w;
        sw += w;
      }
      float dn = fmaxf(sw, 1.0f);
      fR[n][0] = sx/dn; fR[n][1] = sy/dn; fR[n][2] = (sw > 0.f) ? 1.f : 0.f;
    }
  }
  __syncthreads();

  const int p = tid & 31, e0 = p*2, nb = tid >> 5;   // 8 row-groups of 17
  float w10a = W1[e0],   w11a = W1[EMB+e0],   w12a = W1[2*EMB+e0],   b1a = b1[e0];
  float w10b = W1[e0+1], w11b = W1[EMB+e0+1], w12b = W1[2*EMB+e0+1], b1b = b1[e0+1];
  for (int ni = 0; ni < 17; ++ni) {
    int n = nb*17 + ni;
    float xx = fR[n][0], yy = fR[n][1], zz = fR[n][2];
    float va = fmaf(xx,w10a, fmaf(yy,w11a, fmaf(zz,w12a, b1a)));
    float vb = fmaf(xx,w10b, fmaf(yy,w11b, fmaf(zz,w12b, b1b)));
    *(float2*)&hidl[n][e0] = make_float2(fmaxf(va,0.f), fmaxf(vb,0.f));
  }
  float2 w2c[EMB];
  #pragma unroll
  for (int j = 0; j < EMB; ++j) w2c[j] = *(const float2*)&W2[(size_t)j*EMB + e0];
  float b2a = b2[e0], b2b = b2[e0+1];
  __syncthreads();

  float* xo = x + ((size_t)t*BN + (size_t)b*NN)*EMB + e0;
  for (int ni = 0; ni < 17; ++ni) {
    int n = nb*17 + ni;
    float aa = b2a, ab = b2b;
    const float4* h4 = (const float4*)hidl[n];
    #pragma unroll
    for (int j4 = 0; j4 < 16; ++j4) {
      float4 hv = h4[j4];
      aa = fmaf(hv.x, w2c[4*j4+0].x, aa); ab = fmaf(hv.x, w2c[4*j4+0].y, ab);
      aa = fmaf(hv.y, w2c[4*j4+1].x, aa); ab = fmaf(hv.y, w2c[4*j4+1].y, ab);
      aa = fmaf(hv.z, w2c[4*j4+2].x, aa); ab = fmaf(hv.z, w2c[4*j4+2].y, ab);
      aa = fmaf(hv.w, w2c[4*j4+3].x, aa); ab = fmaf(hv.w, w2c[4*j4+3].y, ab);
    }
    *(float2*)&xo[(size_t)n*EMB] = make_float2(aa, ab);
  }
}

// ---------------------------------------------------------------------------
// K2: LSTM. 256 blocks x 1024 threads (16 waves), S=4/5 seqs per block.
// KEY CHANGE vs prev round: the h/x operand is broadcast via v_readlane
// (SGPR operand of the FMA) instead of uniform-address ds_read_b128.
// Rationale: a uniform b128 wave read still moves 64 lanes x 16B = 1 KB
// through the shared per-CU LDS return path (~8-12 cyc); 16 waves x 5 s x 6
// reads were ~5700 cyc/step of LDS pipe = the real bottleneck (bank-conflict
// counter 0, VALUBusy stuck at 60%). Now: ONE ds_read_b32 per (wave,s)
// (lane l holds chunk element l) + 24 readlanes per 96 FMAs.
// Gate layout: lane owns the (i,f,g,o) quad of one j -> zp write and the
// cross-wave reduce are single b128 ops. S is a template param so the hk[S]
// chunk registers stay statically indexed.
// ---------------------------------------------------------------------------
template<int S>
__device__ __forceinline__ void k2_body(
    const float* __restrict__ x, const float* __restrict__ W_ih,
    const float* __restrict__ W_hh, const float* __restrict__ b_ih,
    const float* __restrict__ b_hh, float* __restrict__ r,
    int s0, float* vl, float* zp, float* bsum4)
{
  const int tid = threadIdx.x;
  const int wid = tid >> 6;          // wave 0..15
  const int l   = tid & 63;
  const int kw  = wid & 7;           // k-chunk index (8 chunks of 24)
  const int k0  = kw * 24;
  const int grp = wid >> 3;          // j-group: 0 -> j in [0,64), 1 -> [64,128)
  const int jown = grp*64 + l;       // the j whose 4 gate rows this lane owns

  // --- weights into registers: rows {jown, 128+jown, 256+jown, 384+jown} ---
  float w[4][24];
  #pragma unroll
  for (int i = 0; i < 4; ++i) {
    int g = i*128 + jown;
    #pragma unroll
    for (int j = 0; j < 24; ++j) {
      int k = k0 + j;
      w[i][j] = (k < 64) ? W_ih[(size_t)g*64 + k] : W_hh[(size_t)g*128 + (k-64)];
    }
  }
  #pragma unroll
  for (int i = 0; i < 4; ++i)
    #pragma unroll
    for (int j = 0; j < 24; ++j)
      asm volatile("" : "+v"(w[i][j]));

  const int jr = tid & 127;

  // precomputed r-store address
  float* rp0 = nullptr;
  if (tid < S*128) {
    int s = tid>>7, q = s0+s, b = q/NN, n = q-b*NN;
    rp0 = r + (((size_t)b*TB)*NN + n)*HID + jr;
  }
  const size_t rstep = (size_t)NN*HID;

  // init: biases (float4-packed per j), h=0, x(t=0)
  if (tid < 128) {
    float4 v;
    v.x = b_ih[tid]       + b_hh[tid];
    v.y = b_ih[128+tid]   + b_hh[128+tid];
    v.z = b_ih[256+tid]   + b_hh[256+tid];
    v.w = b_ih[384+tid]   + b_hh[384+tid];
    *(float4*)&bsum4[tid*4] = v;
  }
  if (tid < S*128) vl[(tid>>7)*192 + 64 + (tid&127)] = 0.f;
  if (tid < S*64)  vl[(tid>>6)*192 + (tid&63)] = x[(size_t)s0*EMB + tid];
  __syncthreads();

  float c0 = 0.f;
  const int lc = (l < 24) ? l : 23;   // lanes >=24 alias elem 23 (broadcast, free)

  for (int t = 0; t < TB; ++t) {
    // prefetch x_{t+1} FIRST (oldest vmem entry -> later wait won't drain stores)
    float xpre = 0.f;
    {
      int tp = (t+1 < TB) ? t+1 : t;
      if (tid < S*64) xpre = x[((size_t)tp*BN + s0)*EMB + tid];
    }
    // one ds_read_b32 per seq: lane l holds chunk element l
    float hk[S];
    #pragma unroll
    for (int s = 0; s < S; ++s) hk[s] = vl[s*192 + k0 + lc];
    // partial z: broadcast via readlane (SGPR FMA operand), zero LDS pipe
    #pragma unroll
    for (int s = 0; s < S; ++s) {
      float a0=0.f, a1=0.f, a2=0.f, a3=0.f;
      #pragma unroll
      for (int j = 0; j < 24; ++j) {
        float hv = __int_as_float(__builtin_amdgcn_readlane(__float_as_int(hk[s]), j));
        a0 = fmaf(hv, w[0][j], a0);
        a1 = fmaf(hv, w[1][j], a1);
        a2 = fmaf(hv, w[2][j], a2);
        a3 = fmaf(hv, w[3][j], a3);
      }
      *(float4*)(zp + (size_t)(s*8 + kw)*512 + jown*4) = make_float4(a0,a1,a2,a3);
    }
    bar_lds();
    // fused cross-wave reduce (8 x ds_read_b128) + gates + DIRECT r-store
    if (tid < S*128) {
      int s = tid>>7;
      float4 bz = *(const float4*)&bsum4[jr*4];
      float zi = bz.x, zf = bz.y, zg = bz.z, zo = bz.w;
      #pragma unroll
      for (int ww = 0; ww < 8; ++ww) {
        float4 p = *(const float4*)(zp + (size_t)(s*8 + ww)*512 + jr*4);
        zi += p.x; zf += p.y; zg += p.z; zo += p.w;
      }
      float c = sigf(zf)*c0 + sigf(zi)*tanhf_fast(zg);
      float h = sigf(zo)*tanhf_fast(c);
      c0 = c;
      vl[s*192 + 64 + jr] = h;
      rp0[(size_t)t*rstep] = h;
    }
    // publish prefetched x (vmcnt wait here only covers the x load)
    if (tid < S*64) vl[(tid>>6)*192 + (tid&63)] = xpre;
    bar_lds();
  }
}

__global__ __launch_bounds__(1024, 4) void k2_lstm(
    const float* __restrict__ x, const float* __restrict__ W_ih,
    const float* __restrict__ W_hh, const float* __restrict__ b_ih,
    const float* __restrict__ b_hh, float* __restrict__ r)
{
  __shared__ float vl[5*192];        // per-seq [x(64) | h(128)]
  __shared__ float zp[5*8*512];      // partials [s][kchunk][j][4]  (80 KB)
  __shared__ float bsum4[128*4];     // (b_ih+b_hh) packed {i,f,g,o} per j
  const int blk = blockIdx.x;
  const int s0 = blk*4 + min(blk, 64);   // balanced partition of 1088
  if (blk < 64) k2_body<5>(x, W_ih, W_hh, b_ih, b_hh, r, s0, vl, zp, bsum4);
  else          k2_body<4>(x, W_ih, W_hh, b_ih, b_hh, r, s0, vl, zp, bsum4);
}

// ---------------------------------------------------------------------------
// K3: GAT. s = r@(Wg@a) matvecs; agg in r-space; ONE 16x128x128 GEMM
// H2=[r_roots;aggR]@Wg with coalesced Wg loads and broadcast V^T from LDS.
// ---------------------------------------------------------------------------
__global__ __launch_bounds__(256) void k3_gat(
    const float* __restrict__ r, const float* __restrict__ Wg,
    const float* __restrict__ a_src, const float* __restrict__ a_dst,
    float* __restrict__ rhat)
{
  __shared__ float rl[NN*132];          // r rows padded to 132 floats (71.8 KB)
  __shared__ float waS[HID], waD[HID];
  __shared__ float ssrc[NN], sdst[NN];
  __shared__ float alpha[MM][24];
  __shared__ float aggR[MM][HID];
  __shared__ float v16[HID*20];         // V^T [k][row], row-pad 20 (16B-aligned)
  __shared__ float h2[16][HID];
  const int bt = blockIdx.x;
  const int tid = threadIdx.x;
  const float* rb = r + (size_t)bt*NN*HID;

  // stage r
  {
    const float4* rb4 = (const float4*)rb;
    for (int i = tid; i < NN*32; i += 256) {
      int n = i >> 5, k4 = i & 31;
      *(float4*)&rl[n*132 + k4*4] = rb4[i];
    }
  }
  // wa = Wg @ a  (two 128-dot columns over 256 threads)
  {
    int half = tid >> 7, j = tid & 127;
    const float* av = half ? a_dst : a_src;
    float acc = 0.f;
    for (int k = 0; k < HID; ++k) acc = fmaf(Wg[(size_t)k*HID + j], av[k], acc);
    if (half) waD[j] = acc; else waS[j] = acc;
  }
  __syncthreads();
  // scores
  for (int job = tid; job < 2*NN; job += 256) {
    int n = job >> 1, which = job & 1;
    const float4* rn = (const float4*)&rl[n*132];
    const float4* wa = (const float4*)(which ? waD : waS);
    float acc = 0.f;
    #pragma unroll
    for (int i = 0; i < 32; ++i) {
      float4 a4 = rn[i], b4 = wa[i];
      acc = fmaf(a4.x,b4.x, fmaf(a4.y,b4.y, fmaf(a4.z,b4.z, fmaf(a4.w,b4.w, acc))));
    }
    if (which) sdst[n] = acc; else ssrc[n] = acc;
  }
  __syncthreads();
  // softmax over each root's 23 incoming edges
  if (tid < MM) {
    int m = tid;
    float sd = sdst[m*KR + KP];
    float ev[23]; float mx = -1e30f;
    #pragma unroll
    for (int k = 0; k < 23; ++k) {
      int srcn;
      if (k < KP) srcn = m*KR + k;
      else { int rr = k - KP; rr += (rr >= m) ? 1 : 0; srcn = rr*KR + KP; }
      float e = ssrc[srcn] + sd;
      e = (e > 0.f) ? e : NEG_SLOPE*e;
      ev[k] = e; mx = fmaxf(mx, e);
    }
    float den = 0.f;
    #pragma unroll
    for (int k = 0; k < 23; ++k) { float ex = __expf(ev[k]-mx); ev[k] = ex; den += ex; }
    float inv = 1.f/den;
    #pragma unroll
    for (int k = 0; k < 23; ++k) alpha[m][k] = ev[k]*inv;
  }
  __syncthreads();
  // aggregate in r-space
  {
    int m = tid >> 5, jq = (tid & 31)*4;
    float4 acc = make_float4(0.f,0.f,0.f,0.f);
    #pragma unroll
    for (int k = 0; k < 23; ++k) {
      int srcn;
      if (k < KP) srcn = m*KR + k;
      else { int rr = k - KP; rr += (rr >= m) ? 1 : 0; srcn = rr*KR + KP; }
      float al = alpha[m][k];
      float4 hv = *(const float4*)&rl[srcn*132 + jq];
      acc.x = fmaf(al, hv.x, acc.x); acc.y = fmaf(al, hv.y, acc.y);
      acc.z = fmaf(al, hv.z, acc.z); acc.w = fmaf(al, hv.w, acc.w);
    }
    *(float4*)&aggR[m][jq] = acc;
  }
  __syncthreads();
  // build V^T: v16[k][row] = (row<8 ? r_root[row][k] : aggR[row-8][k])
  for (int idx = tid; idx < 16*HID; idx += 256) {
    int k = idx & 127, row = idx >> 7;
    float v = (row < 8) ? rl[(row*KR + KP)*132 + k] : aggR[row-8][k];
    v16[k*20 + row] = v;
  }
  __syncthreads();
  // H2 = V(16x128) @ Wg(128x128): thread = (row-half, col j).
  // Wg: one coalesced b32/iter (L2-hot); V^T: all-lane-broadcast float4s.
  {
    int half = tid >> 7, j = tid & 127;
    float acc[8] = {0.f,0.f,0.f,0.f,0.f,0.f,0.f,0.f};
    const float* wgp = Wg + j;
    #pragma unroll 4
    for (int k = 0; k < HID; ++k) {
      float wv = wgp[(size_t)k*HID];
      const float4* vv = (const float4*)&v16[k*20 + half*8];
      float4 va = vv[0], vb = vv[1];
      acc[0] = fmaf(va.x, wv, acc[0]); acc[1] = fmaf(va.y, wv, acc[1]);
      acc[2] = fmaf(va.z, wv, acc[2]); acc[3] = fmaf(va.w, wv, acc[3]);
      acc[4] = fmaf(vb.x, wv, acc[4]); acc[5] = fmaf(vb.y, wv, acc[5]);
      acc[6] = fmaf(vb.z, wv, acc[6]); acc[7] = fmaf(vb.w, wv, acc[7]);
    }
    #pragma unroll
    for (int q = 0; q < 8; ++q) h2[half*8 + q][j] = acc[q];
  }
  __syncthreads();
  // output: leaves elu(H2[m]); roots elu(H2[8+m]); coalesced over j
  {
    int j = tid & 127, half = tid >> 7;
    float* out = rhat + (size_t)bt*NN*HID + j;
    for (int ni = 0; ni < 68; ++ni) {
      int n = half*68 + ni;
      int m = n / KR, kk = n - m*KR;
      float v = (kk < KP) ? h2[m][j] : h2[8+m][j];
      v = (v > 0.f) ? v : (__expf(v) - 1.f);
      out[(size_t)n*HID] = v;
    }
  }
}

// ---------------------------------------------------------------------------
extern "C" void kernel_launch(void* const* d_in, const int* in_sizes, int n_in,
                              void* d_out, int out_size, void* d_ws, size_t ws_size,
                              hipStream_t stream) {
  (void)in_sizes; (void)n_in; (void)out_size; (void)ws_size;
  const float* feat  = (const float*)d_in[0];
  const float* W1    = (const float*)d_in[1];
  const float* b1    = (const float*)d_in[2];
  const float* W2    = (const float*)d_in[3];
  const float* b2    = (const float*)d_in[4];
  const float* W_ih  = (const float*)d_in[5];
  const float* W_hh  = (const float*)d_in[6];
  const float* b_ih  = (const float*)d_in[7];
  const float* b_hh  = (const float*)d_in[8];
  const float* Wg    = (const float*)d_in[9];
  const float* a_src = (const float*)d_in[10];
  const float* a_dst = (const float*)d_in[11];

  float* x    = (float*)d_ws;                       // (T, B*N, EMB) fp32 = 35.7 MB
  float* r    = (float*)d_out;                      // (B, T, N, HID)
  float* rhat = r + (size_t)BB*TB*NN*HID;           // (B, T, N, HID)

  k1_mlp<<<BB*TB, 256, 0, stream>>>(feat, W1, b1, W2, b2, x);
  k2_lstm<<<256, 1024, 0, stream>>>(x, W_ih, W_hh, b_ih, b_hh, r);
  k3_gat<<<BB*TB, 256, 0, stream>>>(r, Wg, a_src, a_dst, rhat);
}